// Round 6
// baseline (393.468 us; speedup 1.0000x reference)
//
#include <hip/hip_runtime.h>
#include <hip/hip_bf16.h>
#include <stdint.h>

typedef __bf16 bf16x8 __attribute__((ext_vector_type(8)));
typedef float floatx4 __attribute__((ext_vector_type(4)));

#define RR 147456   // 384*384 rows
#define NC 128      // channels
#define NN 384

union U32B { unsigned int u; __bf16 h[2]; };

__device__ inline floatx4 zero4() { floatx4 v; v[0]=0.f; v[1]=0.f; v[2]=0.f; v[3]=0.f; return v; }
__device__ inline float sigmoidf_(float x) { return 1.f / (1.f + __expf(-x)); }

// ---------------------------------------------------------------------------
// k0: transpose+cast the six fp32 128x128 weights into bf16 wt[slot][n*128+k]
// slots: 0=Wa 1=Wga 2=Wb 3=Wgb 4=Wg 5=Wo. Tiny; L2-resident.
// ---------------------------------------------------------------------------
__global__ __launch_bounds__(256) void k0_wt(
    const float* __restrict__ w0, const float* __restrict__ w1,
    const float* __restrict__ w2, const float* __restrict__ w3,
    const float* __restrict__ w4, const float* __restrict__ w5,
    __bf16* __restrict__ wt)
{
  const float* w;
  switch (blockIdx.x) {
    case 0: w = w0; break; case 1: w = w1; break; case 2: w = w2; break;
    case 3: w = w3; break; case 4: w = w4; break; default: w = w5; break;
  }
  __bf16* out = wt + blockIdx.x * 16384;
  const int t = threadIdx.x;
  for (int it = 0; it < 64; ++it) {
    int f = it * 256 + t;
    int n = f >> 7, k = f & 127;
    out[f] = (__bf16)w[k * 128 + n];   // wt[n][k] = W[k][n]
  }
}

// ---------------------------------------------------------------------------
// k2: per 128-row tile: LN1 fp32 (zn -> bf16 LDS) -> 5 GEMMs, weights staged
// through LDS (known-good r3 codegen path; direct-global-B was
// schedule-dependently wrong in r4/r5 — do not resurrect).
// Wave w owns m-rows w*32..w*32+31 (2 m-tiles of 16).
//   a_t[c][row] = (zn@Wa+ba)*sig(zn@Wga+bga)   (channel-major, bf16)
//   b_t[c][row] = (zn@Wb+bb)*sig(zn@Wgb+bgb)
//   gate[row][c] = sig(zn@Wg+bg)               (natural layout, bf16)
// LDS: zns 34816 + wts 34816 = 69632 B -> 2 blocks/CU.
// ---------------------------------------------------------------------------
__global__ __launch_bounds__(256) void k2_ln_gemm(
    const float* __restrict__ z, const float* __restrict__ ln1g, const float* __restrict__ ln1b,
    const __bf16* __restrict__ wt,
    const float* __restrict__ ba, const float* __restrict__ bga,
    const float* __restrict__ bb, const float* __restrict__ bgb,
    const float* __restrict__ bg,
    __bf16* __restrict__ at, __bf16* __restrict__ bt, __bf16* __restrict__ gate)
{
  __shared__ __align__(16) __bf16 zns[128][136];  // zn tile, padded stride
  __shared__ __align__(16) __bf16 wts[128][136];  // current W^T
  const int t = threadIdx.x;
  const int w = t >> 6, lane = t & 63;
  const int l15 = lane & 15, quad = lane >> 4;
  const int r0 = blockIdx.x * 128;

  // ---- LN1: wave w handles rows w*32..w*32+31, lane holds channels 2l,2l+1
  {
    float gg0 = ln1g[2*lane], gg1 = ln1g[2*lane+1];
    float bb0 = ln1b[2*lane], bb1 = ln1b[2*lane+1];
    for (int rr = 0; rr < 32; ++rr) {
      int row = w * 32 + rr;
      float2 xz = *(const float2*)(z + (size_t)(r0 + row) * NC + 2*lane);
      float x0 = xz.x, x1 = xz.y;
      float s = x0 + x1, q = x0*x0 + x1*x1;
      #pragma unroll
      for (int m = 1; m < 64; m <<= 1) { s += __shfl_xor(s, m); q += __shfl_xor(q, m); }
      float mean = s * (1.f/128.f);
      float var  = q * (1.f/128.f) - mean*mean;
      float rs = rsqrtf(var + 1e-5f);
      U32B uo;
      uo.h[0] = (__bf16)((x0 - mean) * rs * gg0 + bb0);
      uo.h[1] = (__bf16)((x1 - mean) * rs * gg1 + bb1);
      *(unsigned int*)&zns[row][2*lane] = uo.u;
    }
  }
  __syncthreads();

  auto stage = [&](const __bf16* wsrc) {   // wsrc is W^T rows [n][k], bf16
    #pragma unroll
    for (int it = 0; it < 8; ++it) {
      int f = (it * 256 + t) * 8;
      int n = f >> 7, k = f & 127;
      *(uint4*)&wts[n][k] = *(const uint4*)(wsrc + f);
    }
  };
  // 128x128 tile; wave w owns 32 m-rows (2 m-tiles), acc[mt][nt]
  auto gemm = [&](floatx4 (*acc)[8]) {
    #pragma unroll
    for (int mt = 0; mt < 2; ++mt)
      #pragma unroll
      for (int nt = 0; nt < 8; ++nt) acc[mt][nt] = zero4();
    #pragma unroll
    for (int k0 = 0; k0 < 128; k0 += 32) {
      bf16x8 af[2];
      #pragma unroll
      for (int mt = 0; mt < 2; ++mt)
        af[mt] = *(const bf16x8*)&zns[w*32 + mt*16 + l15][k0 + quad*8];
      #pragma unroll
      for (int nt = 0; nt < 8; ++nt) {
        bf16x8 bfr = *(const bf16x8*)&wts[nt*16 + l15][k0 + quad*8];
        #pragma unroll
        for (int mt = 0; mt < 2; ++mt)
          acc[mt][nt] = __builtin_amdgcn_mfma_f32_16x16x32_bf16(af[mt], bfr, acc[mt][nt], 0, 0, 0);
      }
    }
  };
  auto combine_store = [&](floatx4 (*aP)[8], floatx4 (*aG)[8],
                           const float* bia, const float* big, __bf16* dst) {
    #pragma unroll
    for (int mt = 0; mt < 2; ++mt) {
      #pragma unroll
      for (int nt = 0; nt < 8; ++nt) {
        int c = nt*16 + l15;
        float bav = bia[c], bgv = big[c];
        union { uint2 u2; __bf16 h[4]; } pk;
        #pragma unroll
        for (int r = 0; r < 4; ++r) {
          float p  = aP[mt][nt][r] + bav;
          float gg = aG[mt][nt][r] + bgv;
          pk.h[r] = (__bf16)(p * sigmoidf_(gg));
        }
        // 4 consecutive rows at fixed channel -> 8B store, channel-major plane
        *(uint2*)(dst + (size_t)c * RR + r0 + w*32 + mt*16 + quad*4) = pk.u2;
      }
    }
  };

  floatx4 accP[2][8], accG[2][8];

  stage(wt + 0*16384); __syncthreads(); gemm(accP); __syncthreads();
  stage(wt + 1*16384); __syncthreads(); gemm(accG); __syncthreads();
  combine_store(accP, accG, ba, bga, at);
  stage(wt + 2*16384); __syncthreads(); gemm(accP); __syncthreads();
  stage(wt + 3*16384); __syncthreads(); gemm(accG); __syncthreads();
  combine_store(accP, accG, bb, bgb, bt);
  stage(wt + 4*16384); __syncthreads(); gemm(accG);

  // gate: bounce via zns rows just read by this wave (program-order safe,
  // r3-verified pattern), then coalesced store
  #pragma unroll
  for (int mt = 0; mt < 2; ++mt) {
    #pragma unroll
    for (int nt = 0; nt < 8; ++nt) {
      int c = nt*16 + l15;
      float bgv = bg[c];
      #pragma unroll
      for (int r = 0; r < 4; ++r)
        zns[w*32 + mt*16 + quad*4 + r][c] = (__bf16)sigmoidf_(accG[mt][nt][r] + bgv);
    }
  }
  __syncthreads();
  #pragma unroll
  for (int half = 0; half < 2; ++half) {
    // 64 rows x 128 ch per half; thread -> row, channels [(t&3)*32, +32)
    int row = half*64 + (t >> 2), c0 = (t & 3) * 32;
    uint4* dst = (uint4*)(gate + (size_t)(r0 + row) * NC + c0);
    const uint4* src = (const uint4*)&zns[row][c0];
    dst[0] = src[0]; dst[1] = src[1]; dst[2] = src[2]; dst[3] = src[3];
  }
}

// ---------------------------------------------------------------------------
// k3: triangle einsum. Per channel c: o_t[c] = A_c(384x384) @ B_c^T.
// grid (9 tiles, 128 channels); block computes 128x128 o-tile, wave = 64x64.
// ---------------------------------------------------------------------------
__global__ __launch_bounds__(256) void k3_tri(
    const __bf16* __restrict__ at, const __bf16* __restrict__ bt, float* __restrict__ o)
{
  __shared__ __align__(16) __bf16 As[128][72];
  __shared__ __align__(16) __bf16 Bs[128][72];
  const int t = threadIdx.x;
  const int w = t >> 6, lane = t & 63, l15 = lane & 15, quad = lane >> 4;
  const int c = blockIdx.y;
  const int i0 = (blockIdx.x / 3) * 128, j0 = (blockIdx.x % 3) * 128;
  const int wi = w >> 1, wj = w & 1;
  const size_t base = (size_t)c * RR;
  const __bf16* A  = at + base;
  const __bf16* Bp = bt + base;

  floatx4 acc[4][4];
  #pragma unroll
  for (int mt = 0; mt < 4; ++mt)
    #pragma unroll
    for (int nt = 0; nt < 4; ++nt) acc[mt][nt] = zero4();

  for (int kk = 0; kk < NN; kk += 64) {
    #pragma unroll
    for (int s2 = 0; s2 < 4; ++s2) {
      int f = s2 * 2048 + t * 8;        // contiguous across lanes
      int row = f >> 6, k = f & 63;
      *(uint4*)&As[row][k] = *(const uint4*)(A  + (size_t)(i0 + row) * NN + kk + k);
      *(uint4*)&Bs[row][k] = *(const uint4*)(Bp + (size_t)(j0 + row) * NN + kk + k);
    }
    __syncthreads();
    #pragma unroll
    for (int k0 = 0; k0 < 64; k0 += 32) {
      bf16x8 af[4], bfr[4];
      #pragma unroll
      for (int mt = 0; mt < 4; ++mt) af[mt]  = *(const bf16x8*)&As[wi*64 + mt*16 + l15][k0 + quad*8];
      #pragma unroll
      for (int nt = 0; nt < 4; ++nt) bfr[nt] = *(const bf16x8*)&Bs[wj*64 + nt*16 + l15][k0 + quad*8];
      #pragma unroll
      for (int mt = 0; mt < 4; ++mt)
        #pragma unroll
        for (int nt = 0; nt < 4; ++nt)
          acc[mt][nt] = __builtin_amdgcn_mfma_f32_16x16x32_bf16(af[mt], bfr[nt], acc[mt][nt], 0, 0, 0);
    }
    __syncthreads();
  }
  // store fp32, 64B-contiguous per (quad,reg) row
  #pragma unroll
  for (int mt = 0; mt < 4; ++mt) {
    #pragma unroll
    for (int r = 0; r < 4; ++r) {
      int i = i0 + wi*64 + mt*16 + quad*4 + r;
      float* orow = o + base + (size_t)i * NN + j0 + wj*64;
      #pragma unroll
      for (int nt = 0; nt < 4; ++nt) orow[nt*16 + l15] = acc[mt][nt][r];
    }
  }
}

// ---------------------------------------------------------------------------
// k4: per 64-position tile: gather o (channel-major fp32) -> LDS transpose ->
//     LN2 -> MFMA x Wo^T (staged via LDS) -> *gate -> fp32 out  [r3-exact]
// ---------------------------------------------------------------------------
__global__ __launch_bounds__(256) void k4_out(
    const float* __restrict__ o, const __bf16* __restrict__ gate,
    const float* __restrict__ ln2g, const float* __restrict__ ln2b,
    const __bf16* __restrict__ wot, const float* __restrict__ bo,
    float* __restrict__ out)
{
  __shared__ __align__(16) float  osb[64][129];   // o tile [pos][c]
  __shared__ __align__(16) __bf16 ans[64][136];   // normalized tile (bf16)
  __shared__ __align__(16) __bf16 wts[128][136];  // Wo^T
  __shared__ __align__(16) __bf16 gbf[64][136];   // gate tile
  const int t = threadIdx.x;
  const int w = t >> 6, lane = t & 63, l15 = lane & 15, quad = lane >> 4;
  const int r0 = blockIdx.x * 64;

  // gather o: 256B-contiguous per channel plane, transpose into [pos][c]
  #pragma unroll
  for (int it = 0; it < 8; ++it) {
    int f = it * 1024 + t * 4;
    int cx = f >> 6, p = f & 63;
    float4 v = *(const float4*)(o + (size_t)cx * RR + r0 + p);
    osb[p+0][cx] = v.x; osb[p+1][cx] = v.y; osb[p+2][cx] = v.z; osb[p+3][cx] = v.w;
  }
  {
    int row = t >> 2, c0 = (t & 3) * 32;
    const uint4* src = (const uint4*)(gate + (size_t)(r0 + row) * NC + c0);
    uint4* dst = (uint4*)&gbf[row][c0];
    dst[0] = src[0]; dst[1] = src[1]; dst[2] = src[2]; dst[3] = src[3];
  }
  #pragma unroll
  for (int it = 0; it < 8; ++it) {
    int f = (it * 256 + t) * 8;
    int n = f >> 7, k = f & 127;
    *(uint4*)&wts[n][k] = *(const uint4*)(wot + f);
  }
  __syncthreads();

  // LN2 per position (fp32 stats)
  {
    float gg0 = ln2g[2*lane], gg1 = ln2g[2*lane+1];
    float bb0 = ln2b[2*lane], bb1 = ln2b[2*lane+1];
    for (int rr = 0; rr < 16; ++rr) {
      int row = w * 16 + rr;
      float x0 = osb[row][2*lane], x1 = osb[row][2*lane+1];
      float s = x0 + x1, q = x0*x0 + x1*x1;
      #pragma unroll
      for (int m = 1; m < 64; m <<= 1) { s += __shfl_xor(s, m); q += __shfl_xor(q, m); }
      float mean = s * (1.f/128.f);
      float var  = q * (1.f/128.f) - mean*mean;
      float rs = rsqrtf(var + 1e-5f);
      U32B uo;
      uo.h[0] = (__bf16)((x0 - mean) * rs * gg0 + bb0);
      uo.h[1] = (__bf16)((x1 - mean) * rs * gg1 + bb1);
      *(unsigned int*)&ans[row][2*lane] = uo.u;
    }
  }
  __syncthreads();

  floatx4 acc[8];
  #pragma unroll
  for (int nt = 0; nt < 8; ++nt) acc[nt] = zero4();
  #pragma unroll
  for (int k0 = 0; k0 < 128; k0 += 32) {
    bf16x8 af = *(const bf16x8*)&ans[w*16 + l15][k0 + quad*8];
    #pragma unroll
    for (int nt = 0; nt < 8; ++nt) {
      bf16x8 bfr = *(const bf16x8*)&wts[nt*16 + l15][k0 + quad*8];
      acc[nt] = __builtin_amdgcn_mfma_f32_16x16x32_bf16(af, bfr, acc[nt], 0, 0, 0);
    }
  }

  // epilogue: out = gate * (acc + bo), direct fp32 store (16-lane 64B runs)
  #pragma unroll
  for (int nt = 0; nt < 8; ++nt) {
    int c = nt*16 + l15;
    float bov = bo[c];
    #pragma unroll
    for (int r = 0; r < 4; ++r) {
      int rl = w*16 + quad*4 + r;
      out[(size_t)(r0 + rl) * NC + c] = (float)gbf[rl][c] * (acc[nt][r] + bov);
    }
  }
}

// ---------------------------------------------------------------------------
// Workspace layout (bytes):
//   a_t   @ 0          : 147456*128*2 = 37748736   (bf16, channel-major)
//   b_t   @ 37748736   : 37748736
//   gate  @ 75497472   : 37748736                  (bf16, natural layout)
//   o     @ 113246208  : 147456*128*4 = 75497472   (fp32, channel-major)
//   wt    @ 188743680  : 6*16384*2 = 196608        (transposed bf16 weights)
//   total 188940288
// ---------------------------------------------------------------------------
extern "C" void kernel_launch(void* const* d_in, const int* in_sizes, int n_in,
                              void* d_out, int out_size, void* d_ws, size_t ws_size,
                              hipStream_t stream) {
  const float* z    = (const float*)d_in[0];
  const float* l1g  = (const float*)d_in[1];
  const float* l1b  = (const float*)d_in[2];
  const float* l2g  = (const float*)d_in[3];
  const float* l2b  = (const float*)d_in[4];
  const float* Wa   = (const float*)d_in[5];
  const float* ba   = (const float*)d_in[6];
  const float* Wga  = (const float*)d_in[7];
  const float* bga  = (const float*)d_in[8];
  const float* Wb   = (const float*)d_in[9];
  const float* bb   = (const float*)d_in[10];
  const float* Wgb  = (const float*)d_in[11];
  const float* bgb  = (const float*)d_in[12];
  const float* Wg   = (const float*)d_in[13];
  const float* bg   = (const float*)d_in[14];
  const float* Wo   = (const float*)d_in[15];
  const float* bo   = (const float*)d_in[16];

  char* ws = (char*)d_ws;
  __bf16* at_  = (__bf16*)(ws + 0);
  __bf16* bt_  = (__bf16*)(ws + 37748736);
  __bf16* gate = (__bf16*)(ws + 75497472);
  float*  o    = (float*) (ws + 113246208);
  __bf16* wt   = (__bf16*)(ws + 188743680);

  hipLaunchKernelGGL(k0_wt, dim3(6), dim3(256), 0, stream, Wa, Wga, Wb, Wgb, Wg, Wo, wt);
  hipLaunchKernelGGL(k2_ln_gemm, dim3(1152), dim3(256), 0, stream,
                     z, l1g, l1b, wt, ba, bga, bb, bgb, bg, at_, bt_, gate);
  hipLaunchKernelGGL(k3_tri, dim3(9, 128), dim3(256), 0, stream, at_, bt_, o);
  hipLaunchKernelGGL(k4_out, dim3(2304), dim3(256), 0, stream,
                     o, gate, l2g, l2b, wt + 5*16384, bo, (float*)d_out);
}

// Round 7
// 381.330 us; speedup vs baseline: 1.0318x; 1.0318x over previous
//
#include <hip/hip_runtime.h>
#include <hip/hip_bf16.h>
#include <stdint.h>

typedef __bf16 bf16x8 __attribute__((ext_vector_type(8)));
typedef float floatx4 __attribute__((ext_vector_type(4)));

#define RR 147456   // 384*384 rows
#define NC 128      // channels
#define NN 384
#define T_TILES 8   // row-tiles per k2b block; 2304 = 288 * 8

union U32B { unsigned int u; __bf16 h[2]; };

__device__ inline floatx4 zero4() { floatx4 v; v[0]=0.f; v[1]=0.f; v[2]=0.f; v[3]=0.f; return v; }
__device__ inline float sigmoidf_(float x) { return 1.f / (1.f + __expf(-x)); }

// ---------------------------------------------------------------------------
// k0: transpose+cast the six fp32 128x128 weights into bf16 wt[slot][n*128+k]
// slots: 0=Wa 1=Wga 2=Wb 3=Wgb 4=Wg 5=Wo. Tiny; L2-resident. [r3-exact]
// ---------------------------------------------------------------------------
__global__ __launch_bounds__(256) void k0_wt(
    const float* __restrict__ w0, const float* __restrict__ w1,
    const float* __restrict__ w2, const float* __restrict__ w3,
    const float* __restrict__ w4, const float* __restrict__ w5,
    __bf16* __restrict__ wt)
{
  const float* w;
  switch (blockIdx.x) {
    case 0: w = w0; break; case 1: w = w1; break; case 2: w = w2; break;
    case 3: w = w3; break; case 4: w = w4; break; default: w = w5; break;
  }
  __bf16* out = wt + blockIdx.x * 16384;
  const int t = threadIdx.x;
  for (int it = 0; it < 64; ++it) {
    int f = it * 256 + t;
    int n = f >> 7, k = f & 127;
    out[f] = (__bf16)w[k * 128 + n];   // wt[n][k] = W[k][n]
  }
}

// ---------------------------------------------------------------------------
// k2a: LN1 only -> zn (bf16, natural [row][c]) to global. Coalesced.
// Per 64-row block; wave w rows w*16..+15; lane holds channels 2l,2l+1.
// ---------------------------------------------------------------------------
__global__ __launch_bounds__(256) void k2a_ln(
    const float* __restrict__ z, const float* __restrict__ ln1g,
    const float* __restrict__ ln1b, __bf16* __restrict__ zn)
{
  const int t = threadIdx.x;
  const int w = t >> 6, lane = t & 63;
  const int r0 = blockIdx.x * 64;
  float gg0 = ln1g[2*lane], gg1 = ln1g[2*lane+1];
  float bb0 = ln1b[2*lane], bb1 = ln1b[2*lane+1];
  for (int rr = 0; rr < 16; ++rr) {
    int row = w * 16 + rr;
    float2 xz = *(const float2*)(z + (size_t)(r0 + row) * NC + 2*lane);
    float x0 = xz.x, x1 = xz.y;
    float s = x0 + x1, q = x0*x0 + x1*x1;
    #pragma unroll
    for (int m = 1; m < 64; m <<= 1) { s += __shfl_xor(s, m); q += __shfl_xor(q, m); }
    float mean = s * (1.f/128.f);
    float var  = q * (1.f/128.f) - mean*mean;
    float rs = rsqrtf(var + 1e-5f);
    U32B uo;
    uo.h[0] = (__bf16)((x0 - mean) * rs * gg0 + bb0);
    uo.h[1] = (__bf16)((x1 - mean) * rs * gg1 + bb1);
    *(unsigned int*)(zn + (size_t)(r0 + row) * NC + 2*lane) = uo.u;
  }
}

// ---------------------------------------------------------------------------
// k2b: persistent-ish GEMM. grid (288, 3); variant v = blockIdx.y:
//   v0: a_t = (zn@Wa+ba)*sig(zn@Wga+bga)    v1: b_t (Wb,Wgb)    v2: gate (Wg)
// Weights staged into LDS ONCE per block (XOR-swizzled, unpadded 32KB each),
// then 8 row-tiles: zn tile global->LDS, 2 barriers, GEMMs back-to-back.
// LDS = 16K zns + 2x32K weights = 80KB exact -> 2 blocks/CU.
// Swizzle: 8-elem chunk column kc stored at kc^(row%16); both af (row%16=l15)
// and bfr (n%16=l15) reads become 2-way (free). [r6 lesson: don't grow the
// barrier-chained tile; amortize staging across tiles instead]
// ---------------------------------------------------------------------------
__global__ __launch_bounds__(256) void k2b_gemm(
    const __bf16* __restrict__ zn, const __bf16* __restrict__ wt,
    const float* __restrict__ ba, const float* __restrict__ bga,
    const float* __restrict__ bb, const float* __restrict__ bgb,
    const float* __restrict__ bg,
    __bf16* __restrict__ at, __bf16* __restrict__ bt, __bf16* __restrict__ gate)
{
  __shared__ __align__(16) __bf16 zns[64 * 128];
  __shared__ __align__(16) __bf16 wb0[128 * 128];
  __shared__ __align__(16) __bf16 wb1[128 * 128];   // v2: gate bounce scratch
  const int t = threadIdx.x;
  const int w = t >> 6, lane = t & 63;
  const int l15 = lane & 15, quad = lane >> 4;
  const int v = blockIdx.y;

  // ---- stage weights once (natural [n][k] -> swizzled LDS)
  {
    const __bf16* wg0 = wt + (v == 0 ? 0 : v == 1 ? 2 : 4) * 16384;
    const __bf16* wg1 = wt + (v == 0 ? 1 : 3) * 16384;   // unused for v2
    #pragma unroll
    for (int it = 0; it < 8; ++it) {
      int c = it * 256 + t;                 // chunk 0..2047 (16B chunks)
      int n = c >> 4, kc = c & 15;
      int sw = kc ^ (n & 15);
      *(uint4*)&wb0[n * 128 + sw * 8] = *(const uint4*)(wg0 + c * 8);
      if (v < 2)
        *(uint4*)&wb1[n * 128 + sw * 8] = *(const uint4*)(wg1 + c * 8);
    }
  }

  // 64x128 tile GEMM vs a staged weight buffer; wave w owns rows w*16..+15
  auto gemm = [&](const __bf16* wb, floatx4* acc) {
    #pragma unroll
    for (int nt = 0; nt < 8; ++nt) acc[nt] = zero4();
    #pragma unroll
    for (int kb = 0; kb < 4; ++kb) {
      int kc = (kb * 4 + quad) ^ l15;       // swizzled chunk col
      bf16x8 af = *(const bf16x8*)&zns[(w*16 + l15) * 128 + kc * 8];
      #pragma unroll
      for (int nt = 0; nt < 8; ++nt) {
        bf16x8 bfr = *(const bf16x8*)&wb[(nt*16 + l15) * 128 + kc * 8];
        acc[nt] = __builtin_amdgcn_mfma_f32_16x16x32_bf16(af, bfr, acc[nt], 0, 0, 0);
      }
    }
  };

  for (int tile = 0; tile < T_TILES; ++tile) {
    const int r0 = (blockIdx.x * T_TILES + tile) * 64;
    __syncthreads();   // zns/wb1-scratch safe to overwrite (also covers stage)
    // ---- stage zn tile (natural -> swizzled LDS), coalesced reads
    #pragma unroll
    for (int it = 0; it < 4; ++it) {
      int c = it * 256 + t;                 // chunk 0..1023
      int row = c >> 4, kc = c & 15;
      int sw = kc ^ (row & 15);
      *(uint4*)&zns[row * 128 + sw * 8] = *(const uint4*)(zn + (size_t)r0 * NC + c * 8);
    }
    __syncthreads();

    if (v < 2) {
      floatx4 accP[8], accG[8];
      gemm(wb0, accP);
      gemm(wb1, accG);
      const float* biaP = (v == 0) ? ba  : bb;
      const float* biaG = (v == 0) ? bga : bgb;
      __bf16* dst = (v == 0) ? at : bt;
      #pragma unroll
      for (int nt = 0; nt < 8; ++nt) {
        int c = nt*16 + l15;
        float bav = biaP[c], bgv = biaG[c];
        union { uint2 u2; __bf16 h[4]; } pk;
        #pragma unroll
        for (int r = 0; r < 4; ++r) {
          float p  = accP[nt][r] + bav;
          float gg = accG[nt][r] + bgv;
          pk.h[r] = (__bf16)(p * sigmoidf_(gg));
        }
        // 4 consecutive rows at fixed channel -> 8B store, channel-major plane
        *(uint2*)(dst + (size_t)c * RR + r0 + w*16 + quad*4) = pk.u2;
      }
    } else {
      floatx4 accG[8];
      gemm(wb0, accG);
      // bounce via wb1 (padded stride 136) for coalesced natural-layout store
      __bf16* gb = wb1;
      #pragma unroll
      for (int nt = 0; nt < 8; ++nt) {
        int c = nt*16 + l15;
        float bgv = bg[c];
        #pragma unroll
        for (int r = 0; r < 4; ++r)
          gb[(w*16 + quad*4 + r) * 136 + c] = (__bf16)sigmoidf_(accG[nt][r] + bgv);
      }
      __syncthreads();
      int row = t >> 2, c0 = (t & 3) * 32;
      uint4* dstg = (uint4*)(gate + (size_t)(r0 + row) * NC + c0);
      const uint4* src = (const uint4*)&gb[row * 136 + c0];
      dstg[0] = src[0]; dstg[1] = src[1]; dstg[2] = src[2]; dstg[3] = src[3];
    }
  }
}

// ---------------------------------------------------------------------------
// k3: triangle einsum. Per channel c: o_t[c] = A_c(384x384) @ B_c^T. [r3-exact]
// ---------------------------------------------------------------------------
__global__ __launch_bounds__(256) void k3_tri(
    const __bf16* __restrict__ at, const __bf16* __restrict__ bt, float* __restrict__ o)
{
  __shared__ __align__(16) __bf16 As[128][72];
  __shared__ __align__(16) __bf16 Bs[128][72];
  const int t = threadIdx.x;
  const int w = t >> 6, lane = t & 63, l15 = lane & 15, quad = lane >> 4;
  const int c = blockIdx.y;
  const int i0 = (blockIdx.x / 3) * 128, j0 = (blockIdx.x % 3) * 128;
  const int wi = w >> 1, wj = w & 1;
  const size_t base = (size_t)c * RR;
  const __bf16* A  = at + base;
  const __bf16* Bp = bt + base;

  floatx4 acc[4][4];
  #pragma unroll
  for (int mt = 0; mt < 4; ++mt)
    #pragma unroll
    for (int nt = 0; nt < 4; ++nt) acc[mt][nt] = zero4();

  for (int kk = 0; kk < NN; kk += 64) {
    #pragma unroll
    for (int s2 = 0; s2 < 4; ++s2) {
      int f = s2 * 2048 + t * 8;        // contiguous across lanes
      int row = f >> 6, k = f & 63;
      *(uint4*)&As[row][k] = *(const uint4*)(A  + (size_t)(i0 + row) * NN + kk + k);
      *(uint4*)&Bs[row][k] = *(const uint4*)(Bp + (size_t)(j0 + row) * NN + kk + k);
    }
    __syncthreads();
    #pragma unroll
    for (int k0 = 0; k0 < 64; k0 += 32) {
      bf16x8 af[4], bfr[4];
      #pragma unroll
      for (int mt = 0; mt < 4; ++mt) af[mt]  = *(const bf16x8*)&As[wi*64 + mt*16 + l15][k0 + quad*8];
      #pragma unroll
      for (int nt = 0; nt < 4; ++nt) bfr[nt] = *(const bf16x8*)&Bs[wj*64 + nt*16 + l15][k0 + quad*8];
      #pragma unroll
      for (int mt = 0; mt < 4; ++mt)
        #pragma unroll
        for (int nt = 0; nt < 4; ++nt)
          acc[mt][nt] = __builtin_amdgcn_mfma_f32_16x16x32_bf16(af[mt], bfr[nt], acc[mt][nt], 0, 0, 0);
    }
    __syncthreads();
  }
  #pragma unroll
  for (int mt = 0; mt < 4; ++mt) {
    #pragma unroll
    for (int r = 0; r < 4; ++r) {
      int i = i0 + wi*64 + mt*16 + quad*4 + r;
      float* orow = o + base + (size_t)i * NN + j0 + wj*64;
      #pragma unroll
      for (int nt = 0; nt < 4; ++nt) orow[nt*16 + l15] = acc[mt][nt][r];
    }
  }
}

// ---------------------------------------------------------------------------
// k4: per 64-position tile: gather o (channel-major fp32) -> LDS transpose ->
//     LN2 -> MFMA x Wo^T (staged via LDS) -> *gate -> fp32 out  [r3-exact]
// ---------------------------------------------------------------------------
__global__ __launch_bounds__(256) void k4_out(
    const float* __restrict__ o, const __bf16* __restrict__ gate,
    const float* __restrict__ ln2g, const float* __restrict__ ln2b,
    const __bf16* __restrict__ wot, const float* __restrict__ bo,
    float* __restrict__ out)
{
  __shared__ __align__(16) float  osb[64][129];   // o tile [pos][c]
  __shared__ __align__(16) __bf16 ans[64][136];   // normalized tile (bf16)
  __shared__ __align__(16) __bf16 wts[128][136];  // Wo^T
  __shared__ __align__(16) __bf16 gbf[64][136];   // gate tile
  const int t = threadIdx.x;
  const int w = t >> 6, lane = t & 63, l15 = lane & 15, quad = lane >> 4;
  const int r0 = blockIdx.x * 64;

  #pragma unroll
  for (int it = 0; it < 8; ++it) {
    int f = it * 1024 + t * 4;
    int cx = f >> 6, p = f & 63;
    float4 v = *(const float4*)(o + (size_t)cx * RR + r0 + p);
    osb[p+0][cx] = v.x; osb[p+1][cx] = v.y; osb[p+2][cx] = v.z; osb[p+3][cx] = v.w;
  }
  {
    int row = t >> 2, c0 = (t & 3) * 32;
    const uint4* src = (const uint4*)(gate + (size_t)(r0 + row) * NC + c0);
    uint4* dst = (uint4*)&gbf[row][c0];
    dst[0] = src[0]; dst[1] = src[1]; dst[2] = src[2]; dst[3] = src[3];
  }
  #pragma unroll
  for (int it = 0; it < 8; ++it) {
    int f = (it * 256 + t) * 8;
    int n = f >> 7, k = f & 127;
    *(uint4*)&wts[n][k] = *(const uint4*)(wot + f);
  }
  __syncthreads();

  {
    float gg0 = ln2g[2*lane], gg1 = ln2g[2*lane+1];
    float bb0 = ln2b[2*lane], bb1 = ln2b[2*lane+1];
    for (int rr = 0; rr < 16; ++rr) {
      int row = w * 16 + rr;
      float x0 = osb[row][2*lane], x1 = osb[row][2*lane+1];
      float s = x0 + x1, q = x0*x0 + x1*x1;
      #pragma unroll
      for (int m = 1; m < 64; m <<= 1) { s += __shfl_xor(s, m); q += __shfl_xor(q, m); }
      float mean = s * (1.f/128.f);
      float var  = q * (1.f/128.f) - mean*mean;
      float rs = rsqrtf(var + 1e-5f);
      U32B uo;
      uo.h[0] = (__bf16)((x0 - mean) * rs * gg0 + bb0);
      uo.h[1] = (__bf16)((x1 - mean) * rs * gg1 + bb1);
      *(unsigned int*)&ans[row][2*lane] = uo.u;
    }
  }
  __syncthreads();

  floatx4 acc[8];
  #pragma unroll
  for (int nt = 0; nt < 8; ++nt) acc[nt] = zero4();
  #pragma unroll
  for (int k0 = 0; k0 < 128; k0 += 32) {
    bf16x8 af = *(const bf16x8*)&ans[w*16 + l15][k0 + quad*8];
    #pragma unroll
    for (int nt = 0; nt < 8; ++nt) {
      bf16x8 bfr = *(const bf16x8*)&wts[nt*16 + l15][k0 + quad*8];
      acc[nt] = __builtin_amdgcn_mfma_f32_16x16x32_bf16(af, bfr, acc[nt], 0, 0, 0);
    }
  }

  #pragma unroll
  for (int nt = 0; nt < 8; ++nt) {
    int c = nt*16 + l15;
    float bov = bo[c];
    #pragma unroll
    for (int r = 0; r < 4; ++r) {
      int rl = w*16 + quad*4 + r;
      out[(size_t)(r0 + rl) * NC + c] = (float)gbf[rl][c] * (acc[nt][r] + bov);
    }
  }
}

// ---------------------------------------------------------------------------
// Workspace layout (bytes):
//   a_t   @ 0          : 37748736   (bf16, channel-major)
//   b_t   @ 37748736   : 37748736
//   gate  @ 75497472   : 37748736   (bf16, natural layout)
//   o     @ 113246208  : 75497472   (fp32, channel-major)  [zn bf16 overlaps
//                                    here during k2a/k2b; o written by k3 after]
//   wt    @ 188743680  : 196608     (transposed bf16 weights)
//   total 188940288
// ---------------------------------------------------------------------------
extern "C" void kernel_launch(void* const* d_in, const int* in_sizes, int n_in,
                              void* d_out, int out_size, void* d_ws, size_t ws_size,
                              hipStream_t stream) {
  const float* z    = (const float*)d_in[0];
  const float* l1g  = (const float*)d_in[1];
  const float* l1b  = (const float*)d_in[2];
  const float* l2g  = (const float*)d_in[3];
  const float* l2b  = (const float*)d_in[4];
  const float* Wa   = (const float*)d_in[5];
  const float* ba   = (const float*)d_in[6];
  const float* Wga  = (const float*)d_in[7];
  const float* bga  = (const float*)d_in[8];
  const float* Wb   = (const float*)d_in[9];
  const float* bb   = (const float*)d_in[10];
  const float* Wgb  = (const float*)d_in[11];
  const float* bgb  = (const float*)d_in[12];
  const float* Wg   = (const float*)d_in[13];
  const float* bg   = (const float*)d_in[14];
  const float* Wo   = (const float*)d_in[15];
  const float* bo   = (const float*)d_in[16];

  char* ws = (char*)d_ws;
  __bf16* at_  = (__bf16*)(ws + 0);
  __bf16* bt_  = (__bf16*)(ws + 37748736);
  __bf16* gate = (__bf16*)(ws + 75497472);
  float*  o    = (float*) (ws + 113246208);
  __bf16* zn   = (__bf16*)(ws + 113246208);   // overlaps o (dead until k3)
  __bf16* wt   = (__bf16*)(ws + 188743680);

  hipLaunchKernelGGL(k0_wt, dim3(6), dim3(256), 0, stream, Wa, Wga, Wb, Wgb, Wg, Wo, wt);
  hipLaunchKernelGGL(k2a_ln, dim3(2304), dim3(256), 0, stream, z, l1g, l1b, zn);
  hipLaunchKernelGGL(k2b_gemm, dim3(288, 3), dim3(256), 0, stream,
                     zn, wt, ba, bga, bb, bgb, bg, at_, bt_, gate);
  hipLaunchKernelGGL(k3_tri, dim3(9, 128), dim3(256), 0, stream, at_, bt_, o);
  hipLaunchKernelGGL(k4_out, dim3(2304), dim3(256), 0, stream,
                     o, gate, l2g, l2b, wt + 5*16384, bo, (float*)d_out);
}